// Round 8
// baseline (98.581 us; speedup 1.0000x reference)
//
#include <hip/hip_runtime.h>
#include <hip/hip_bf16.h>
#include <cstdint>

// B=65536, D=128, H=256, O=8, E=8
// Algebra: no activation between head Linears -> y = h @ (W1 W2) + (b1 W2 + b2).
// Single merged kernel (grid=512 = 2 blocks/CU, co-resident by capacity:
// __launch_bounds__(256,2) + 64KB LDS -> manual flag sync is deadlock-free).
// Blocks 0..255 compute prep (Wf; 0..15 also wsP; 16 also bfuse), signal via
// agent-scope counter; all blocks spin, then run the validated round-5 body.
// ws layout: wsP uint4[4096] @0 (64KB) | wfP bf16 @65536 (32KB) |
//            bfuse f32[64] @98304 | sync u32 @98560
using bf16x8 = __attribute__((ext_vector_type(8))) __bf16;
using f32x4  = __attribute__((ext_vector_type(4))) float;

__device__ __forceinline__ unsigned short bf16b(float f) {
    __bf16 h = (__bf16)f;                       // RNE; pairs fuse to v_cvt_pk_bf16_f32
    return __builtin_bit_cast(unsigned short, h);
}
__device__ __forceinline__ unsigned pack2(float a, float b) {
    return (unsigned)bf16b(a) | ((unsigned)bf16b(b) << 16);
}

__global__ __launch_bounds__(256, 2) void mono_kernel(
    const float* __restrict__ x,
    const int* __restrict__ phases,
    const float* __restrict__ bs,
    const float* __restrict__ Ws,
    const float* __restrict__ b1,
    const float* __restrict__ W1,
    const float* __restrict__ W2,
    const float* __restrict__ b2,
    uint4* __restrict__ wsP,
    unsigned short* __restrict__ wfP,
    float* __restrict__ bfuse,
    unsigned* __restrict__ sync_c,
    float* __restrict__ out) {
    __shared__ __align__(16) char lds[65536];
    char* xs0 = lds;                     // [64][128] bf16, swz: addr ^= (row&7)<<4
    char* xs1 = lds + 16384;
    char* hs  = lds + 32768;             // [64][256] bf16 main phase; w2sT f32 in prep

    const int bid = blockIdx.x, tid = threadIdx.x;
    const int lane = tid & 63;
    const int wv = tid >> 6;
    const int l15 = lane & 15;
    const int lhi = lane >> 4;
    const int blk0 = bid * 128;          // two 64-row tiles per block

    const float4* xg = (const float4*)x;

    // ---- 1. issue x loads for BOTH tiles (land under prep/spin) ----
    float4 a0[4], d0[4], a1[4], d1[4];
    #pragma unroll
    for (int it = 0; it < 4; ++it) {
        int c = it * 256 + tid;          // chunk of 8 floats in a 64x128 tile
        int row = c >> 4, col8 = c & 15;
        int gi0 = (blk0 + row) * 32 + col8 * 2;
        a0[it] = xg[gi0]; d0[it] = xg[gi0 + 1];
        int gi1 = (blk0 + 64 + row) * 32 + col8 * 2;
        a1[it] = xg[gi1]; d1[it] = xg[gi1 + 1];
    }

    // ---- 2. prep (blocks 0..255 only) ----
    if (bid < 256) {
        float (*w2sT)[256] = (float (*)[256])hs;     // 8KB inside hs region
        const int e = bid >> 5, mc = bid & 31;
        const float* W2e = W2 + (size_t)e * 2048;
        #pragma unroll
        for (int h = 0; h < 2; ++h) {
            int f4 = h * 256 + tid;                  // 512 float4 total
            float4 v = ((const float4*)W2e)[f4];
            int k = f4 >> 1, o4 = (f4 & 1) * 4;
            w2sT[o4 + 0][k] = v.x;
            w2sT[o4 + 1][k] = v.y;
            w2sT[o4 + 2][k] = v.z;
            w2sT[o4 + 3][k] = v.w;
        }
        __syncthreads();
        const int mloc = tid >> 5, kg = tid & 31;    // k = kg + i*32
        const int m = mc * 8 + mloc;
        const float* w1row = W1 + ((size_t)e * 256 + m) * 256;
        float w1v[8];
        #pragma unroll
        for (int i = 0; i < 8; ++i) w1v[i] = w1row[kg + i * 32];
        float acc[8] = {0,0,0,0,0,0,0,0};
        #pragma unroll
        for (int i = 0; i < 8; ++i) {
            int k = kg + i * 32;
            #pragma unroll
            for (int o = 0; o < 8; ++o) acc[o] += w1v[i] * w2sT[o][k];
        }
        #pragma unroll
        for (int o = 0; o < 8; ++o) {
            acc[o] += __shfl_xor(acc[o], 1);
            acc[o] += __shfl_xor(acc[o], 2);
            acc[o] += __shfl_xor(acc[o], 4);
            acc[o] += __shfl_xor(acc[o], 8);
            acc[o] += __shfl_xor(acc[o], 16);
        }
        if (kg == 0) {
            // scatter into wfP fragment order: element (c=e*8+o, m)
            const int kgf  = m >> 5;
            const int lhif = (m >> 3) & 3;
            const int j    = m & 7;
            #pragma unroll
            for (int o = 0; o < 8; ++o) {
                int c = e * 8 + o;
                int lanef = lhif * 16 + (c & 15);
                int F = (kgf * 4 + (c >> 4)) * 64 + lanef;
                wfP[(size_t)F * 8 + j] = bf16b(acc[o]);
            }
        }
        if (bid < 16) {
            // wsP pack: this block owns (kg,hi) = (bid>>2, bid&3)
            const int kgp = bid >> 2, hip = bid & 3;
            const int n  = wv * 64 + hip * 16 + l15;
            const int k0 = kgp * 32 + lhi * 8;
            float w[8];
            #pragma unroll
            for (int j = 0; j < 8; ++j)
                w[j] = Ws[(size_t)(k0 + j) * 256 + n];
            uint4 u;
            u.x = pack2(w[0], w[1]); u.y = pack2(w[2], w[3]);
            u.z = pack2(w[4], w[5]); u.w = pack2(w[6], w[7]);
            wsP[((kgp * 4 + hip) * 4 + wv) * 64 + lane] = u;
        }
        if (bid == 16 && tid < 64) {
            const int e2 = tid >> 3, o = tid & 7;
            float acc2 = b2[e2 * 8 + o];
            for (int k = 0; k < 256; ++k)
                acc2 += b1[e2 * 256 + k] * W2[((size_t)(e2 * 256 + k)) * 8 + o];
            bfuse[e2 * 8 + o] = acc2;
        }
        // release: every thread fences its own stores, then one signal
        __threadfence();
        __syncthreads();
        if (tid == 0)
            __hip_atomic_fetch_add(sync_c, 1u, __ATOMIC_RELAXED,
                                   __HIP_MEMORY_SCOPE_AGENT);
    }

    // ---- 3. convert + write both xs buffers (overlaps others' prep) ----
    #pragma unroll
    for (int it = 0; it < 4; ++it) {
        int c = it * 256 + tid;
        int row = c >> 4, col8 = c & 15;
        unsigned addr = (unsigned)(row * 256 + col8 * 16);
        addr ^= (unsigned)((row & 7) << 4);
        uint4 u;
        u.x = pack2(a0[it].x, a0[it].y); u.y = pack2(a0[it].z, a0[it].w);
        u.z = pack2(d0[it].x, d0[it].y); u.w = pack2(d0[it].z, d0[it].w);
        *(uint4*)(xs0 + addr) = u;
        uint4 v;
        v.x = pack2(a1[it].x, a1[it].y); v.y = pack2(a1[it].z, a1[it].w);
        v.z = pack2(d1[it].x, d1[it].y); v.w = pack2(d1[it].z, d1[it].w);
        *(uint4*)(xs1 + addr) = v;
    }

    // ---- 4. spin until all 256 prep blocks signalled ----
    while (__hip_atomic_load(sync_c, __ATOMIC_RELAXED,
                             __HIP_MEMORY_SCOPE_AGENT) < 256u)
        __builtin_amdgcn_s_sleep(8);
    __threadfence();                     // acquire: invalidate caches

    // ---- 5. weight fragments (coalesced, round-5-validated layout) ----
    const uint4* wfPq = (const uint4*)wfP;
    bf16x8 wsA[4][4];                    // A[n][k], n = wv*64+hi*16+l15
    #pragma unroll
    for (int hi = 0; hi < 4; ++hi)
        #pragma unroll
        for (int kg = 0; kg < 4; ++kg)
            wsA[hi][kg] = __builtin_bit_cast(bf16x8,
                wsP[((kg * 4 + hi) * 4 + wv) * 64 + lane]);
    bf16x8 wfB[8];                       // B[k][c], c = wv*16+l15
    #pragma unroll
    for (int kg = 0; kg < 8; ++kg)
        wfB[kg] = __builtin_bit_cast(bf16x8, wfPq[(kg * 4 + wv) * 64 + lane]);
    const float bfv = bfuse[wv * 16 + l15];
    const int myE = wv * 2 + (l15 >> 3);
    const int co  = l15 & 7;

    // ---- 6. main loop: round-5 body ----
    #pragma unroll
    for (int t = 0; t < 2; ++t) {
        const char* xs = t ? xs1 : xs0;
        const int row0 = blk0 + t * 64;
        __syncthreads();                 // t0: xs ready / all past spin; t1: hs reads done

        // GEMM1: h^T[n][b] = WsT @ x^T
        f32x4 acc1[4][4];                // [hi][bi]
        #pragma unroll
        for (int hi = 0; hi < 4; ++hi)
            #pragma unroll
            for (int bi = 0; bi < 4; ++bi)
                acc1[hi][bi] = (f32x4){0.f, 0.f, 0.f, 0.f};
        #pragma unroll
        for (int kg = 0; kg < 4; ++kg) {
            bf16x8 xb[4];
            #pragma unroll
            for (int bi = 0; bi < 4; ++bi) {
                int b = bi * 16 + l15;
                unsigned addr = (unsigned)(b * 256 + (kg * 32 + lhi * 8) * 2);
                addr ^= (unsigned)((b & 7) << 4);
                xb[bi] = *(const bf16x8*)(xs + addr);
            }
            __builtin_amdgcn_s_setprio(1);
            #pragma unroll
            for (int hi = 0; hi < 4; ++hi)
                #pragma unroll
                for (int bi = 0; bi < 4; ++bi)
                    acc1[hi][bi] = __builtin_amdgcn_mfma_f32_16x16x32_bf16(
                        wsA[hi][kg], xb[bi], acc1[hi][bi], 0, 0, 0);
            __builtin_amdgcn_s_setprio(0);
        }

        // h-write: relu(acc1 + bs), conflict-free ds_write_b64
        f32x4 bsr[4];
        #pragma unroll
        for (int hi = 0; hi < 4; ++hi)
            bsr[hi] = *(const f32x4*)(bs + wv * 64 + hi * 16 + lhi * 4);
        #pragma unroll
        for (int hi = 0; hi < 4; ++hi)
            #pragma unroll
            for (int bi = 0; bi < 4; ++bi) {
                float v0 = acc1[hi][bi][0] + bsr[hi][0]; v0 = v0 > 0.f ? v0 : 0.f;
                float v1 = acc1[hi][bi][1] + bsr[hi][1]; v1 = v1 > 0.f ? v1 : 0.f;
                float v2 = acc1[hi][bi][2] + bsr[hi][2]; v2 = v2 > 0.f ? v2 : 0.f;
                float v3 = acc1[hi][bi][3] + bsr[hi][3]; v3 = v3 > 0.f ? v3 : 0.f;
                uint2 u; u.x = pack2(v0, v1); u.y = pack2(v2, v3);
                int b = bi * 16 + l15;
                int n0 = wv * 64 + hi * 16 + lhi * 4;
                unsigned addr = (unsigned)(b * 512 + n0 * 2);
                addr ^= (unsigned)((b & 7) << 4);
                *(uint2*)(hs + addr) = u;
            }
        __syncthreads();                 // hs ready

        // GEMM2: y[b][c] = h @ WfT + bfuse
        f32x4 acc2[4];
        #pragma unroll
        for (int mi = 0; mi < 4; ++mi)
            acc2[mi] = (f32x4){bfv, bfv, bfv, bfv};
        #pragma unroll
        for (int kg = 0; kg < 8; ++kg) {
            bf16x8 ha[4];
            #pragma unroll
            for (int mi = 0; mi < 4; ++mi) {
                int b = mi * 16 + l15;
                unsigned addr = (unsigned)(b * 512 + (kg * 32 + lhi * 8) * 2);
                addr ^= (unsigned)((b & 7) << 4);
                ha[mi] = *(const bf16x8*)(hs + addr);
            }
            __builtin_amdgcn_s_setprio(1);
            #pragma unroll
            for (int mi = 0; mi < 4; ++mi)
                acc2[mi] = __builtin_amdgcn_mfma_f32_16x16x32_bf16(
                    ha[mi], wfB[kg], acc2[mi], 0, 0, 0);
            __builtin_amdgcn_s_setprio(0);
        }

        // routed predicated stores
        #pragma unroll
        for (int mi = 0; mi < 4; ++mi)
            #pragma unroll
            for (int r = 0; r < 4; ++r) {
                int b = mi * 16 + lhi * 4 + r;
                int e = phases[row0 + b];
                if (e == myE)
                    out[(size_t)(row0 + b) * 8 + co] = acc2[mi][r];
            }
    }
}

extern "C" void kernel_launch(void* const* d_in, const int* in_sizes, int n_in,
                              void* d_out, int out_size, void* d_ws, size_t ws_size,
                              hipStream_t stream) {
    const float* x      = (const float*)d_in[0];
    const int*   phases = (const int*)d_in[1];
    const float* Ws     = (const float*)d_in[2];
    const float* bs     = (const float*)d_in[3];
    const float* W1     = (const float*)d_in[4];
    const float* b1     = (const float*)d_in[5];
    const float* W2     = (const float*)d_in[6];
    const float* b2     = (const float*)d_in[7];
    float* out = (float*)d_out;

    uint4*          wsP    = (uint4*)d_ws;
    unsigned short* wfP    = (unsigned short*)((char*)d_ws + 65536);
    float*          bfuse  = (float*)((char*)d_ws + 98304);
    unsigned*       sync_c = (unsigned*)((char*)d_ws + 98560);

    hipMemsetAsync((void*)sync_c, 0, 4, stream);   // reset flag (replay-safe)
    mono_kernel<<<512, 256, 0, stream>>>(
        x, phases, bs, Ws, b1, W1, W2, b2, wsP, wfP, bfuse, sync_c, out);
}

// Round 9
// 82.816 us; speedup vs baseline: 1.1904x; 1.1904x over previous
//
#include <hip/hip_runtime.h>
#include <hip/hip_bf16.h>
#include <cstdint>

// B=65536, D=128, H=256, O=8, E=8
// Algebra: no activation between head Linears -> y = h @ (W1 W2) + (b1 W2 + b2).
// Single merged kernel (grid=512 = 2 blocks/CU, co-resident by capacity:
// __launch_bounds__(256,2) + 64KB LDS; empirically verified co-resident in r8).
// Blocks 0..255 prep (Wf; 0..15 also wsP; 16 also bfuse) FIRST, signal, then
// stage x. Other blocks stage x, then ONE LANE per block spins (r8 lesson:
// 131K spinning threads crush the coherence point -> 512 spinners only).
// ws layout: wsP uint4[4096] @0 (64KB) | wfP bf16 @65536 (32KB) |
//            bfuse f32[64] @98304 | sync u32 @98560
using bf16x8 = __attribute__((ext_vector_type(8))) __bf16;
using f32x4  = __attribute__((ext_vector_type(4))) float;

__device__ __forceinline__ unsigned short bf16b(float f) {
    __bf16 h = (__bf16)f;                       // RNE; pairs fuse to v_cvt_pk_bf16_f32
    return __builtin_bit_cast(unsigned short, h);
}
__device__ __forceinline__ unsigned pack2(float a, float b) {
    return (unsigned)bf16b(a) | ((unsigned)bf16b(b) << 16);
}

__global__ __launch_bounds__(256, 2) void mono_kernel(
    const float* __restrict__ x,
    const int* __restrict__ phases,
    const float* __restrict__ bs,
    const float* __restrict__ Ws,
    const float* __restrict__ b1,
    const float* __restrict__ W1,
    const float* __restrict__ W2,
    const float* __restrict__ b2,
    uint4* __restrict__ wsP,
    unsigned short* __restrict__ wfP,
    float* __restrict__ bfuse,
    unsigned* __restrict__ sync_c,
    float* __restrict__ out) {
    __shared__ __align__(16) char lds[65536];
    char* xs0 = lds;                     // [64][128] bf16, swz: addr ^= (row&7)<<4
    char* xs1 = lds + 16384;
    char* hs  = lds + 32768;             // [64][256] bf16 main phase; w2sT f32 in prep

    const int bid = blockIdx.x, tid = threadIdx.x;
    const int lane = tid & 63;
    const int wv = tid >> 6;
    const int l15 = lane & 15;
    const int lhi = lane >> 4;
    const int blk0 = bid * 128;          // two 64-row tiles per block

    const float4* xg = (const float4*)x;

    // ---- prep blocks: weights FIRST (no vmcnt drain behind x), signal early ----
    if (bid < 256) {
        float (*w2sT)[256] = (float (*)[256])hs;     // 8KB inside hs region
        const int e = bid >> 5, mc = bid & 31;
        const float* W2e = W2 + (size_t)e * 2048;
        #pragma unroll
        for (int h = 0; h < 2; ++h) {
            int f4 = h * 256 + tid;                  // 512 float4 total
            float4 v = ((const float4*)W2e)[f4];
            int k = f4 >> 1, o4 = (f4 & 1) * 4;
            w2sT[o4 + 0][k] = v.x;
            w2sT[o4 + 1][k] = v.y;
            w2sT[o4 + 2][k] = v.z;
            w2sT[o4 + 3][k] = v.w;
        }
        __syncthreads();
        const int mloc = tid >> 5, kg = tid & 31;    // k = kg + i*32
        const int m = mc * 8 + mloc;
        const float* w1row = W1 + ((size_t)e * 256 + m) * 256;
        float w1v[8];
        #pragma unroll
        for (int i = 0; i < 8; ++i) w1v[i] = w1row[kg + i * 32];
        float acc[8] = {0,0,0,0,0,0,0,0};
        #pragma unroll
        for (int i = 0; i < 8; ++i) {
            int k = kg + i * 32;
            #pragma unroll
            for (int o = 0; o < 8; ++o) acc[o] += w1v[i] * w2sT[o][k];
        }
        #pragma unroll
        for (int o = 0; o < 8; ++o) {
            acc[o] += __shfl_xor(acc[o], 1);
            acc[o] += __shfl_xor(acc[o], 2);
            acc[o] += __shfl_xor(acc[o], 4);
            acc[o] += __shfl_xor(acc[o], 8);
            acc[o] += __shfl_xor(acc[o], 16);
        }
        if (kg == 0) {
            // scatter into wfP fragment order: element (c=e*8+o, m)
            const int kgf  = m >> 5;
            const int lhif = (m >> 3) & 3;
            const int j    = m & 7;
            #pragma unroll
            for (int o = 0; o < 8; ++o) {
                int c = e * 8 + o;
                int lanef = lhif * 16 + (c & 15);
                int F = (kgf * 4 + (c >> 4)) * 64 + lanef;
                wfP[(size_t)F * 8 + j] = bf16b(acc[o]);
            }
        }
        if (bid < 16) {
            // wsP pack: this block owns (kg,hi) = (bid>>2, bid&3)
            const int kgp = bid >> 2, hip = bid & 3;
            const int n  = wv * 64 + hip * 16 + l15;
            const int k0 = kgp * 32 + lhi * 8;
            float w[8];
            #pragma unroll
            for (int j = 0; j < 8; ++j)
                w[j] = Ws[(size_t)(k0 + j) * 256 + n];
            uint4 u;
            u.x = pack2(w[0], w[1]); u.y = pack2(w[2], w[3]);
            u.z = pack2(w[4], w[5]); u.w = pack2(w[6], w[7]);
            wsP[((kgp * 4 + hip) * 4 + wv) * 64 + lane] = u;
        }
        if (bid == 16) {
            // bfuse = b1@W2 + b2, k-parallel: 8 e x 32 k-lanes
            const int e2 = tid >> 5, l = tid & 31;
            float ac[8] = {0,0,0,0,0,0,0,0};
            #pragma unroll
            for (int i = 0; i < 8; ++i) {
                int k = l * 8 + i;
                float a = b1[e2 * 256 + k];
                const float* w2r = W2 + ((size_t)(e2 * 256 + k)) * 8;
                #pragma unroll
                for (int o = 0; o < 8; ++o) ac[o] += a * w2r[o];
            }
            #pragma unroll
            for (int o = 0; o < 8; ++o) {
                ac[o] += __shfl_xor(ac[o], 1);
                ac[o] += __shfl_xor(ac[o], 2);
                ac[o] += __shfl_xor(ac[o], 4);
                ac[o] += __shfl_xor(ac[o], 8);
                ac[o] += __shfl_xor(ac[o], 16);
            }
            if (l == 0) {
                #pragma unroll
                for (int o = 0; o < 8; ++o)
                    bfuse[e2 * 8 + o] = ac[o] + b2[e2 * 8 + o];
            }
        }
        // release: fence own stores, block-barrier, single signal
        __threadfence();
        __syncthreads();
        if (tid == 0)
            __hip_atomic_fetch_add(sync_c, 1u, __ATOMIC_RELAXED,
                                   __HIP_MEMORY_SCOPE_AGENT);
    }

    // ---- stage x: issue both tiles' loads, convert to bf16, write LDS ----
    {
        float4 a0[4], d0[4], a1[4], d1[4];
        #pragma unroll
        for (int it = 0; it < 4; ++it) {
            int c = it * 256 + tid;      // chunk of 8 floats in a 64x128 tile
            int row = c >> 4, col8 = c & 15;
            int gi0 = (blk0 + row) * 32 + col8 * 2;
            a0[it] = xg[gi0]; d0[it] = xg[gi0 + 1];
            int gi1 = (blk0 + 64 + row) * 32 + col8 * 2;
            a1[it] = xg[gi1]; d1[it] = xg[gi1 + 1];
        }
        #pragma unroll
        for (int it = 0; it < 4; ++it) {
            int c = it * 256 + tid;
            int row = c >> 4, col8 = c & 15;
            unsigned addr = (unsigned)(row * 256 + col8 * 16);
            addr ^= (unsigned)((row & 7) << 4);
            uint4 u;
            u.x = pack2(a0[it].x, a0[it].y); u.y = pack2(a0[it].z, a0[it].w);
            u.z = pack2(d0[it].x, d0[it].y); u.w = pack2(d0[it].z, d0[it].w);
            *(uint4*)(xs0 + addr) = u;
            uint4 v;
            v.x = pack2(a1[it].x, a1[it].y); v.y = pack2(a1[it].z, a1[it].w);
            v.z = pack2(d1[it].x, d1[it].y); v.w = pack2(d1[it].z, d1[it].w);
            *(uint4*)(xs1 + addr) = v;
        }
    }

    // ---- wait: ONE lane spins per block (r8 lesson), barrier covers the rest ----
    if (tid == 0) {
        while (__hip_atomic_load(sync_c, __ATOMIC_RELAXED,
                                 __HIP_MEMORY_SCOPE_AGENT) < 256u)
            __builtin_amdgcn_s_sleep(16);
    }
    __syncthreads();                     // also: xs0/xs1 writes visible
    __threadfence();                     // acquire side

    // ---- weight fragments (coalesced, round-5-validated layout) ----
    const uint4* wfPq = (const uint4*)wfP;
    bf16x8 wsA[4][4];                    // A[n][k], n = wv*64+hi*16+l15
    #pragma unroll
    for (int hi = 0; hi < 4; ++hi)
        #pragma unroll
        for (int kg = 0; kg < 4; ++kg)
            wsA[hi][kg] = __builtin_bit_cast(bf16x8,
                wsP[((kg * 4 + hi) * 4 + wv) * 64 + lane]);
    bf16x8 wfB[8];                       // B[k][c], c = wv*16+l15
    #pragma unroll
    for (int kg = 0; kg < 8; ++kg)
        wfB[kg] = __builtin_bit_cast(bf16x8, wfPq[(kg * 4 + wv) * 64 + lane]);
    const float bfv = bfuse[wv * 16 + l15];
    const int myE = wv * 2 + (l15 >> 3);
    const int co  = l15 & 7;

    // ---- main loop: round-5 validated body ----
    #pragma unroll
    for (int t = 0; t < 2; ++t) {
        const char* xs = t ? xs1 : xs0;
        const int row0 = blk0 + t * 64;

        // GEMM1: h^T[n][b] = WsT @ x^T
        f32x4 acc1[4][4];                // [hi][bi]
        #pragma unroll
        for (int hi = 0; hi < 4; ++hi)
            #pragma unroll
            for (int bi = 0; bi < 4; ++bi)
                acc1[hi][bi] = (f32x4){0.f, 0.f, 0.f, 0.f};
        #pragma unroll
        for (int kg = 0; kg < 4; ++kg) {
            bf16x8 xb[4];
            #pragma unroll
            for (int bi = 0; bi < 4; ++bi) {
                int b = bi * 16 + l15;
                unsigned addr = (unsigned)(b * 256 + (kg * 32 + lhi * 8) * 2);
                addr ^= (unsigned)((b & 7) << 4);
                xb[bi] = *(const bf16x8*)(xs + addr);
            }
            __builtin_amdgcn_s_setprio(1);
            #pragma unroll
            for (int hi = 0; hi < 4; ++hi)
                #pragma unroll
                for (int bi = 0; bi < 4; ++bi)
                    acc1[hi][bi] = __builtin_amdgcn_mfma_f32_16x16x32_bf16(
                        wsA[hi][kg], xb[bi], acc1[hi][bi], 0, 0, 0);
            __builtin_amdgcn_s_setprio(0);
        }

        // h-write: relu(acc1 + bs), conflict-free ds_write_b64
        f32x4 bsr[4];
        #pragma unroll
        for (int hi = 0; hi < 4; ++hi)
            bsr[hi] = *(const f32x4*)(bs + wv * 64 + hi * 16 + lhi * 4);
        #pragma unroll
        for (int hi = 0; hi < 4; ++hi)
            #pragma unroll
            for (int bi = 0; bi < 4; ++bi) {
                float v0 = acc1[hi][bi][0] + bsr[hi][0]; v0 = v0 > 0.f ? v0 : 0.f;
                float v1 = acc1[hi][bi][1] + bsr[hi][1]; v1 = v1 > 0.f ? v1 : 0.f;
                float v2 = acc1[hi][bi][2] + bsr[hi][2]; v2 = v2 > 0.f ? v2 : 0.f;
                float v3 = acc1[hi][bi][3] + bsr[hi][3]; v3 = v3 > 0.f ? v3 : 0.f;
                uint2 u; u.x = pack2(v0, v1); u.y = pack2(v2, v3);
                int b = bi * 16 + l15;
                int n0 = wv * 64 + hi * 16 + lhi * 4;
                unsigned addr = (unsigned)(b * 512 + n0 * 2);
                addr ^= (unsigned)((b & 7) << 4);
                *(uint2*)(hs + addr) = u;
            }
        __syncthreads();                 // hs ready

        // GEMM2: y[b][c] = h @ WfT + bfuse
        f32x4 acc2[4];
        #pragma unroll
        for (int mi = 0; mi < 4; ++mi)
            acc2[mi] = (f32x4){bfv, bfv, bfv, bfv};
        #pragma unroll
        for (int kg = 0; kg < 8; ++kg) {
            bf16x8 ha[4];
            #pragma unroll
            for (int mi = 0; mi < 4; ++mi) {
                int b = mi * 16 + l15;
                unsigned addr = (unsigned)(b * 512 + (kg * 32 + lhi * 8) * 2);
                addr ^= (unsigned)((b & 7) << 4);
                ha[mi] = *(const bf16x8*)(hs + addr);
            }
            __builtin_amdgcn_s_setprio(1);
            #pragma unroll
            for (int mi = 0; mi < 4; ++mi)
                acc2[mi] = __builtin_amdgcn_mfma_f32_16x16x32_bf16(
                    ha[mi], wfB[kg], acc2[mi], 0, 0, 0);
            __builtin_amdgcn_s_setprio(0);
        }

        // routed predicated stores
        #pragma unroll
        for (int mi = 0; mi < 4; ++mi)
            #pragma unroll
            for (int r = 0; r < 4; ++r) {
                int b = mi * 16 + lhi * 4 + r;
                int e = phases[row0 + b];
                if (e == myE)
                    out[(size_t)(row0 + b) * 8 + co] = acc2[mi][r];
            }
        if (t == 0) __syncthreads();     // hs reads done before tile-1 h-write
    }
}

extern "C" void kernel_launch(void* const* d_in, const int* in_sizes, int n_in,
                              void* d_out, int out_size, void* d_ws, size_t ws_size,
                              hipStream_t stream) {
    const float* x      = (const float*)d_in[0];
    const int*   phases = (const int*)d_in[1];
    const float* Ws     = (const float*)d_in[2];
    const float* bs     = (const float*)d_in[3];
    const float* W1     = (const float*)d_in[4];
    const float* b1     = (const float*)d_in[5];
    const float* W2     = (const float*)d_in[6];
    const float* b2     = (const float*)d_in[7];
    float* out = (float*)d_out;

    uint4*          wsP    = (uint4*)d_ws;
    unsigned short* wfP    = (unsigned short*)((char*)d_ws + 65536);
    float*          bfuse  = (float*)((char*)d_ws + 98304);
    unsigned*       sync_c = (unsigned*)((char*)d_ws + 98560);

    hipMemsetAsync((void*)sync_c, 0, 4, stream);   // reset flag (replay-safe)
    mono_kernel<<<512, 256, 0, stream>>>(
        x, phases, bs, Ws, b1, W1, W2, b2, wsP, wfP, bfuse, sync_c, out);
}

// Round 10
// 49.394 us; speedup vs baseline: 1.9958x; 1.6766x over previous
//
#include <hip/hip_runtime.h>
#include <hip/hip_bf16.h>
#include <cstdint>

// B=65536, D=128, H=256, O=8, E=8
// Algebra: no activation between head Linears -> y = h @ (W1 W2) + (b1 W2 + b2).
// Two launches (merged-kernel global sync measured 80-98us in r8/r9 - abandoned).
// ws layout (weights pre-packed in MFMA FRAGMENT ORDER for coalesced loads):
//   wsP  uint4[4096]  @0      (64KB): wsP[((kg*4+hi)*4+wv)*64+lane] = A-frag of Ws^T
//   wfP  uint4[2048]  @65536  (32KB): wfP[(kg*4+wv)*64+lane]        = B-frag of (W1@W2)^T
//   bfuse f32[64]     @98304:          bfuse[e*8+o] = (b1[e]@W2[e])[o] + b2[e][o]

using bf16x8 = __attribute__((ext_vector_type(8))) __bf16;
using f32x4  = __attribute__((ext_vector_type(4))) float;

__device__ __forceinline__ unsigned short bf16b(float f) {
    __bf16 h = (__bf16)f;                       // RNE; pairs fuse to v_cvt_pk_bf16_f32
    return __builtin_bit_cast(unsigned short, h);
}
__device__ __forceinline__ unsigned pack2(float a, float b) {
    return (unsigned)bf16b(a) | ((unsigned)bf16b(b) << 16);
}

// ---------------------------------------------------------------------------
// Prep v5: 273 blocks. Same math as validated r5; W2+W1 loads both issued
// before the LDS scatter so the two HBM round trips overlap.
// ---------------------------------------------------------------------------
__global__ void prep_kernel(const float* __restrict__ Ws,
                            const float* __restrict__ b1,
                            const float* __restrict__ W1,
                            const float* __restrict__ W2,
                            const float* __restrict__ b2,
                            uint4* __restrict__ wsP,
                            unsigned short* __restrict__ wfP,
                            float* __restrict__ bfuse) {
    const int bid = blockIdx.x, tid = threadIdx.x;
    if (bid < 256) {
        __shared__ float w2sT[8][256];               // W2[e]^T : [o][k]
        const int e = bid >> 5, mc = bid & 31;
        const float* W2e = W2 + (size_t)e * 2048;
        // issue W2 loads (oldest)
        float4 v0 = ((const float4*)W2e)[tid];
        float4 v1 = ((const float4*)W2e)[256 + tid];
        // issue W1 loads (newer -> stay outstanding through the LDS scatter)
        const int mloc = tid >> 5, kg = tid & 31;    // k = kg + i*32
        const int m = mc * 8 + mloc;
        const float* w1row = W1 + ((size_t)e * 256 + m) * 256;
        float w1v[8];
        #pragma unroll
        for (int i = 0; i < 8; ++i) w1v[i] = w1row[kg + i * 32];
        // scatter W2 into LDS (waits only on v0/v1)
        {
            int f4 = tid, k = f4 >> 1, o4 = (f4 & 1) * 4;
            w2sT[o4 + 0][k] = v0.x; w2sT[o4 + 1][k] = v0.y;
            w2sT[o4 + 2][k] = v0.z; w2sT[o4 + 3][k] = v0.w;
            f4 = 256 + tid; k = f4 >> 1; o4 = (f4 & 1) * 4;
            w2sT[o4 + 0][k] = v1.x; w2sT[o4 + 1][k] = v1.y;
            w2sT[o4 + 2][k] = v1.z; w2sT[o4 + 3][k] = v1.w;
        }
        __syncthreads();
        float acc[8] = {0,0,0,0,0,0,0,0};
        #pragma unroll
        for (int i = 0; i < 8; ++i) {
            int k = kg + i * 32;
            #pragma unroll
            for (int o = 0; o < 8; ++o) acc[o] += w1v[i] * w2sT[o][k];
        }
        #pragma unroll
        for (int o = 0; o < 8; ++o) {
            acc[o] += __shfl_xor(acc[o], 1);
            acc[o] += __shfl_xor(acc[o], 2);
            acc[o] += __shfl_xor(acc[o], 4);
            acc[o] += __shfl_xor(acc[o], 8);
            acc[o] += __shfl_xor(acc[o], 16);
        }
        if (kg == 0) {
            // scatter into wfP fragment order: element (c=e*8+o, m)
            const int kgf  = m >> 5;
            const int lhif = (m >> 3) & 3;
            const int j    = m & 7;
            #pragma unroll
            for (int o = 0; o < 8; ++o) {
                int c = e * 8 + o;
                int lanef = lhif * 16 + (c & 15);
                int F = (kgf * 4 + (c >> 4)) * 64 + lanef;
                wfP[(size_t)F * 8 + j] = bf16b(acc[o]);
            }
        }
    } else if (bid < 272) {
        // wsP: block encodes (kg,hi); thread encodes (wv,lane)
        const int b2i = bid - 256;
        const int kg = b2i >> 2, hi = b2i & 3;
        const int wv = tid >> 6, lane = tid & 63;
        const int l15 = lane & 15, lhi = lane >> 4;
        const int n  = wv * 64 + hi * 16 + l15;
        const int k0 = kg * 32 + lhi * 8;
        float w[8];
        #pragma unroll
        for (int j = 0; j < 8; ++j)
            w[j] = Ws[(size_t)(k0 + j) * 256 + n];
        uint4 u;
        u.x = pack2(w[0], w[1]); u.y = pack2(w[2], w[3]);
        u.z = pack2(w[4], w[5]); u.w = pack2(w[6], w[7]);
        wsP[((kg * 4 + hi) * 4 + wv) * 64 + lane] = u;
    } else {
        const int e = tid >> 5, l = tid & 31;
        float acc[8] = {0,0,0,0,0,0,0,0};
        #pragma unroll
        for (int i = 0; i < 8; ++i) {
            int k = l * 8 + i;
            float a = b1[e * 256 + k];
            const float* w2r = W2 + ((size_t)(e * 256 + k)) * 8;
            #pragma unroll
            for (int o = 0; o < 8; ++o) acc[o] += a * w2r[o];
        }
        #pragma unroll
        for (int o = 0; o < 8; ++o) {
            acc[o] += __shfl_xor(acc[o], 1);
            acc[o] += __shfl_xor(acc[o], 2);
            acc[o] += __shfl_xor(acc[o], 4);
            acc[o] += __shfl_xor(acc[o], 8);
            acc[o] += __shfl_xor(acc[o], 16);
        }
        if (l == 0) {
            #pragma unroll
            for (int o = 0; o < 8; ++o)
                bfuse[e * 8 + o] = acc[o] + b2[e * 8 + o];
        }
    }
}

// ---------------------------------------------------------------------------
// Fused v8: deep M-pipeline. grid=256 (1 block/CU), 256 rows/block as 4
// pipelined 64-row tiles. xs double-buffered (2x16KB) + hs 32KB = 64KB LDS.
// Per tile: issue x(t+1) loads | GEMM1(t) covers latency | h-write | BAR
// (drains x(t+1)) | write xs[(t+1)&1] | GEMM2(t) | stores | BAR.
// Weights loaded once per block (96KB/CU, half of r5). Body = r5-validated.
// ---------------------------------------------------------------------------
__global__ __launch_bounds__(256, 2) void fused_kernel(
    const float* __restrict__ x,
    const int* __restrict__ phases,
    const float* __restrict__ bs,
    const uint4* __restrict__ wsP,
    const uint4* __restrict__ wfP,
    const float* __restrict__ bfuse,
    float* __restrict__ out) {
    __shared__ __align__(16) char lds[65536];
    char* xs0 = lds;                     // [64][128] bf16, swz: addr ^= (row&7)<<4
    char* xs1 = lds + 16384;
    char* hs  = lds + 32768;             // [64][256] bf16, swz: addr ^= (row&7)<<4

    const int tid = threadIdx.x;
    const int lane = tid & 63;
    const int wv = tid >> 6;
    const int l15 = lane & 15;
    const int lhi = lane >> 4;
    const int blk0 = blockIdx.x * 256;   // four 64-row tiles per block

    const float4* xg = (const float4*)x;

    // ---- prologue: issue tile-0 x loads, then weights, then stage xs0 ----
    float4 a0[4], d0[4];
    #pragma unroll
    for (int it = 0; it < 4; ++it) {
        int c = it * 256 + tid;          // chunk of 8 floats in a 64x128 tile
        int row = c >> 4, col8 = c & 15;
        int gi = (blk0 + row) * 32 + col8 * 2;
        a0[it] = xg[gi]; d0[it] = xg[gi + 1];
    }
    bf16x8 wsA[4][4];                    // A[n][k], n = wv*64+hi*16+l15
    #pragma unroll
    for (int hi = 0; hi < 4; ++hi)
        #pragma unroll
        for (int kg = 0; kg < 4; ++kg)
            wsA[hi][kg] = __builtin_bit_cast(bf16x8,
                wsP[((kg * 4 + hi) * 4 + wv) * 64 + lane]);
    bf16x8 wfB[8];                       // B[k][c], c = wv*16+l15
    #pragma unroll
    for (int kg = 0; kg < 8; ++kg)
        wfB[kg] = __builtin_bit_cast(bf16x8, wfP[(kg * 4 + wv) * 64 + lane]);
    f32x4 bsv[4];
    #pragma unroll
    for (int hi = 0; hi < 4; ++hi)
        bsv[hi] = *(const f32x4*)(bs + wv * 64 + hi * 16 + lhi * 4);
    const float bfv = bfuse[wv * 16 + l15];
    const int myE = wv * 2 + (l15 >> 3);
    const int co  = l15 & 7;

    #pragma unroll
    for (int it = 0; it < 4; ++it) {
        int c = it * 256 + tid;
        int row = c >> 4, col8 = c & 15;
        unsigned addr = (unsigned)(row * 256 + col8 * 16);
        addr ^= (unsigned)((row & 7) << 4);
        uint4 u;
        u.x = pack2(a0[it].x, a0[it].y); u.y = pack2(a0[it].z, a0[it].w);
        u.z = pack2(d0[it].x, d0[it].y); u.w = pack2(d0[it].z, d0[it].w);
        *(uint4*)(xs0 + addr) = u;
    }
    __syncthreads();                     // BAR P: xs0 ready

    #pragma unroll
    for (int t = 0; t < 4; ++t) {
        const char* xs  = (t & 1) ? xs1 : xs0;
        char*       xsn = (t & 1) ? xs0 : xs1;
        const int row0 = blk0 + t * 64;

        // ---- issue next-tile x loads (latency covered by GEMM1) ----
        float4 pa[4], pd[4];
        if (t < 3) {
            int nrow0 = row0 + 64;
            #pragma unroll
            for (int it = 0; it < 4; ++it) {
                int c = it * 256 + tid;
                int row = c >> 4, col8 = c & 15;
                int gi = (nrow0 + row) * 32 + col8 * 2;
                pa[it] = xg[gi]; pd[it] = xg[gi + 1];
            }
        }

        // ---- GEMM1: h^T[n][b] = WsT @ x^T ----
        f32x4 acc1[4][4];                // [hi][bi]
        #pragma unroll
        for (int hi = 0; hi < 4; ++hi)
            #pragma unroll
            for (int bi = 0; bi < 4; ++bi)
                acc1[hi][bi] = (f32x4){0.f, 0.f, 0.f, 0.f};
        #pragma unroll
        for (int kg = 0; kg < 4; ++kg) {
            bf16x8 xb[4];
            #pragma unroll
            for (int bi = 0; bi < 4; ++bi) {
                int b = bi * 16 + l15;
                unsigned addr = (unsigned)(b * 256 + (kg * 32 + lhi * 8) * 2);
                addr ^= (unsigned)((b & 7) << 4);
                xb[bi] = *(const bf16x8*)(xs + addr);
            }
            __builtin_amdgcn_s_setprio(1);
            #pragma unroll
            for (int hi = 0; hi < 4; ++hi)
                #pragma unroll
                for (int bi = 0; bi < 4; ++bi)
                    acc1[hi][bi] = __builtin_amdgcn_mfma_f32_16x16x32_bf16(
                        wsA[hi][kg], xb[bi], acc1[hi][bi], 0, 0, 0);
            __builtin_amdgcn_s_setprio(0);
        }

        // ---- h-write: relu(acc1 + bs), conflict-free ds_write_b64 ----
        #pragma unroll
        for (int hi = 0; hi < 4; ++hi)
            #pragma unroll
            for (int bi = 0; bi < 4; ++bi) {
                float v0 = acc1[hi][bi][0] + bsv[hi][0]; v0 = v0 > 0.f ? v0 : 0.f;
                float v1 = acc1[hi][bi][1] + bsv[hi][1]; v1 = v1 > 0.f ? v1 : 0.f;
                float v2 = acc1[hi][bi][2] + bsv[hi][2]; v2 = v2 > 0.f ? v2 : 0.f;
                float v3 = acc1[hi][bi][3] + bsv[hi][3]; v3 = v3 > 0.f ? v3 : 0.f;
                uint2 u; u.x = pack2(v0, v1); u.y = pack2(v2, v3);
                int b = bi * 16 + l15;
                int n0 = wv * 64 + hi * 16 + lhi * 4;
                unsigned addr = (unsigned)(b * 512 + n0 * 2);
                addr ^= (unsigned)((b & 7) << 4);
                *(uint2*)(hs + addr) = u;
            }
        __syncthreads();                 // BAR B: hs ready; GEMM1 xs reads done;
                                         //        vmcnt drained -> pa/pd landed

        // ---- write next tile into xs[(t+1)&1] (overlaps GEMM2) ----
        if (t < 3) {
            #pragma unroll
            for (int it = 0; it < 4; ++it) {
                int c = it * 256 + tid;
                int row = c >> 4, col8 = c & 15;
                unsigned addr = (unsigned)(row * 256 + col8 * 16);
                addr ^= (unsigned)((row & 7) << 4);
                uint4 u;
                u.x = pack2(pa[it].x, pa[it].y); u.y = pack2(pa[it].z, pa[it].w);
                u.z = pack2(pd[it].x, pd[it].y); u.w = pack2(pd[it].z, pd[it].w);
                *(uint4*)(xsn + addr) = u;
            }
        }

        // ---- GEMM2: y[b][c] = h @ WfT + bfuse ----
        f32x4 acc2[4];
        #pragma unroll
        for (int mi = 0; mi < 4; ++mi)
            acc2[mi] = (f32x4){bfv, bfv, bfv, bfv};
        #pragma unroll
        for (int kg = 0; kg < 8; ++kg) {
            bf16x8 ha[4];
            #pragma unroll
            for (int mi = 0; mi < 4; ++mi) {
                int b = mi * 16 + l15;
                unsigned addr = (unsigned)(b * 512 + (kg * 32 + lhi * 8) * 2);
                addr ^= (unsigned)((b & 7) << 4);
                ha[mi] = *(const bf16x8*)(hs + addr);
            }
            __builtin_amdgcn_s_setprio(1);
            #pragma unroll
            for (int mi = 0; mi < 4; ++mi)
                acc2[mi] = __builtin_amdgcn_mfma_f32_16x16x32_bf16(
                    ha[mi], wfB[kg], acc2[mi], 0, 0, 0);
            __builtin_amdgcn_s_setprio(0);
        }

        // ---- routed predicated stores ----
        #pragma unroll
        for (int mi = 0; mi < 4; ++mi)
            #pragma unroll
            for (int r = 0; r < 4; ++r) {
                int b = mi * 16 + lhi * 4 + r;
                int e = phases[row0 + b];
                if (e == myE)
                    out[(size_t)(row0 + b) * 8 + co] = acc2[mi][r];
            }
        if (t < 3) __syncthreads();      // BAR C: GEMM2 hs reads done; xsn visible
    }
}

extern "C" void kernel_launch(void* const* d_in, const int* in_sizes, int n_in,
                              void* d_out, int out_size, void* d_ws, size_t ws_size,
                              hipStream_t stream) {
    const float* x      = (const float*)d_in[0];
    const int*   phases = (const int*)d_in[1];
    const float* Ws     = (const float*)d_in[2];
    const float* bs     = (const float*)d_in[3];
    const float* W1     = (const float*)d_in[4];
    const float* b1     = (const float*)d_in[5];
    const float* W2     = (const float*)d_in[6];
    const float* b2     = (const float*)d_in[7];
    float* out = (float*)d_out;

    uint4*          wsP   = (uint4*)d_ws;
    unsigned short* wfP   = (unsigned short*)((char*)d_ws + 65536);
    float*          bfuse = (float*)((char*)d_ws + 98304);

    prep_kernel<<<273, 256, 0, stream>>>(Ws, b1, W1, W2, b2,
                                         wsP, wfP, bfuse);
    fused_kernel<<<256, 256, 0, stream>>>(
        x, phases, bs, wsP, (const uint4*)wfP, bfuse, out);
}

// Round 11
// 38.157 us; speedup vs baseline: 2.5836x; 1.2945x over previous
//
#include <hip/hip_runtime.h>
#include <hip/hip_bf16.h>
#include <cstdint>

// B=65536, D=128, H=256, O=8, E=8
// Algebra: no activation between head Linears -> y = h @ (W1 W2) + (b1 W2 + b2).
// ws layout (weights pre-packed in MFMA FRAGMENT ORDER for coalesced loads):
//   wsP  uint4[4096]  @0      (64KB): wsP[((kg*4+hi)*4+wv)*64+lane] = A-frag of Ws^T
//   wfP  uint4[2048]  @65536  (32KB): wfP[(kg*4+wv)*64+lane]        = B-frag of (W1@W2)^T
//   bfuse f32[64]     @98304:          bfuse[e*8+o] = (b1[e]@W2[e])[o] + b2[e][o]

using bf16x8 = __attribute__((ext_vector_type(8))) __bf16;
using f32x4  = __attribute__((ext_vector_type(4))) float;

__device__ __forceinline__ unsigned short bf16b(float f) {
    __bf16 h = (__bf16)f;                       // RNE; pairs fuse to v_cvt_pk_bf16_f32
    return __builtin_bit_cast(unsigned short, h);
}
__device__ __forceinline__ unsigned pack2(float a, float b) {
    return (unsigned)bf16b(a) | ((unsigned)bf16b(b) << 16);
}

// ---------------------------------------------------------------------------
// Prep v5 (validated r9/r10): 273 blocks.
// ---------------------------------------------------------------------------
__global__ void prep_kernel(const float* __restrict__ Ws,
                            const float* __restrict__ b1,
                            const float* __restrict__ W1,
                            const float* __restrict__ W2,
                            const float* __restrict__ b2,
                            uint4* __restrict__ wsP,
                            unsigned short* __restrict__ wfP,
                            float* __restrict__ bfuse) {
    const int bid = blockIdx.x, tid = threadIdx.x;
    if (bid < 256) {
        __shared__ float w2sT[8][256];               // W2[e]^T : [o][k]
        const int e = bid >> 5, mc = bid & 31;
        const float* W2e = W2 + (size_t)e * 2048;
        float4 v0 = ((const float4*)W2e)[tid];
        float4 v1 = ((const float4*)W2e)[256 + tid];
        const int mloc = tid >> 5, kg = tid & 31;    // k = kg + i*32
        const int m = mc * 8 + mloc;
        const float* w1row = W1 + ((size_t)e * 256 + m) * 256;
        float w1v[8];
        #pragma unroll
        for (int i = 0; i < 8; ++i) w1v[i] = w1row[kg + i * 32];
        {
            int f4 = tid, k = f4 >> 1, o4 = (f4 & 1) * 4;
            w2sT[o4 + 0][k] = v0.x; w2sT[o4 + 1][k] = v0.y;
            w2sT[o4 + 2][k] = v0.z; w2sT[o4 + 3][k] = v0.w;
            f4 = 256 + tid; k = f4 >> 1; o4 = (f4 & 1) * 4;
            w2sT[o4 + 0][k] = v1.x; w2sT[o4 + 1][k] = v1.y;
            w2sT[o4 + 2][k] = v1.z; w2sT[o4 + 3][k] = v1.w;
        }
        __syncthreads();
        float acc[8] = {0,0,0,0,0,0,0,0};
        #pragma unroll
        for (int i = 0; i < 8; ++i) {
            int k = kg + i * 32;
            #pragma unroll
            for (int o = 0; o < 8; ++o) acc[o] += w1v[i] * w2sT[o][k];
        }
        #pragma unroll
        for (int o = 0; o < 8; ++o) {
            acc[o] += __shfl_xor(acc[o], 1);
            acc[o] += __shfl_xor(acc[o], 2);
            acc[o] += __shfl_xor(acc[o], 4);
            acc[o] += __shfl_xor(acc[o], 8);
            acc[o] += __shfl_xor(acc[o], 16);
        }
        if (kg == 0) {
            const int kgf  = m >> 5;
            const int lhif = (m >> 3) & 3;
            const int j    = m & 7;
            #pragma unroll
            for (int o = 0; o < 8; ++o) {
                int c = e * 8 + o;
                int lanef = lhif * 16 + (c & 15);
                int F = (kgf * 4 + (c >> 4)) * 64 + lanef;
                wfP[(size_t)F * 8 + j] = bf16b(acc[o]);
            }
        }
    } else if (bid < 272) {
        const int b2i = bid - 256;
        const int kg = b2i >> 2, hi = b2i & 3;
        const int wv = tid >> 6, lane = tid & 63;
        const int l15 = lane & 15, lhi = lane >> 4;
        const int n  = wv * 64 + hi * 16 + l15;
        const int k0 = kg * 32 + lhi * 8;
        float w[8];
        #pragma unroll
        for (int j = 0; j < 8; ++j)
            w[j] = Ws[(size_t)(k0 + j) * 256 + n];
        uint4 u;
        u.x = pack2(w[0], w[1]); u.y = pack2(w[2], w[3]);
        u.z = pack2(w[4], w[5]); u.w = pack2(w[6], w[7]);
        wsP[((kg * 4 + hi) * 4 + wv) * 64 + lane] = u;
    } else {
        const int e = tid >> 5, l = tid & 31;
        float acc[8] = {0,0,0,0,0,0,0,0};
        #pragma unroll
        for (int i = 0; i < 8; ++i) {
            int k = l * 8 + i;
            float a = b1[e * 256 + k];
            const float* w2r = W2 + ((size_t)(e * 256 + k)) * 8;
            #pragma unroll
            for (int o = 0; o < 8; ++o) acc[o] += a * w2r[o];
        }
        #pragma unroll
        for (int o = 0; o < 8; ++o) {
            acc[o] += __shfl_xor(acc[o], 1);
            acc[o] += __shfl_xor(acc[o], 2);
            acc[o] += __shfl_xor(acc[o], 4);
            acc[o] += __shfl_xor(acc[o], 8);
            acc[o] += __shfl_xor(acc[o], 16);
        }
        if (l == 0) {
            #pragma unroll
            for (int o = 0; o < 8; ++o)
                bfuse[e * 8 + o] = acc[o] + b2[e * 8 + o];
        }
    }
}

// ---------------------------------------------------------------------------
// Fused v9: DIRECT-GLOBAL B-fragments. The GEMM1 B-frag for lane l is
// x[b = bi*16+(l&15)][k0..k0+7] with k0 = kg*32+(l>>4)*8 -- 32 CONTIGUOUS
// bytes of row-major x. So: no xs LDS, no staging pass, no prefetch regs
// held across barriers (the r7/r10 spill trap). One 64-row tile per block,
// grid=1024, LDS = hs 32KB only, ONE barrier per block.
// Flow: issue x(32xfloat4)+wsA | cvt->xb | issue wfB | GEMM1 (pure reg) |
//       issue bs/bfuse/phases | h-write | BAR | GEMM2 (hs) | routed stores.
// No launch-bounds min-waves (r6/r7 lesson: forcing occupancy -> spill).
// ---------------------------------------------------------------------------
__global__ __launch_bounds__(256) void fused_kernel(
    const float* __restrict__ x,
    const int* __restrict__ phases,
    const float* __restrict__ bs,
    const uint4* __restrict__ wsP,
    const uint4* __restrict__ wfP,
    const float* __restrict__ bfuse,
    float* __restrict__ out) {
    __shared__ __align__(16) char hs[32768];   // [64][256] bf16, swz: addr ^= (b&7)<<4

    const int tid = threadIdx.x;
    const int lane = tid & 63;
    const int wv = tid >> 6;
    const int l15 = lane & 15;
    const int lhi = lane >> 4;
    const int row0 = blockIdx.x * 64;

    const float4* xg = (const float4*)x;

    // ---- issue x fragment loads: 32 x float4 (one HBM/L3 round trip) ----
    float4 xr[4][8];                     // [kg][bi*2+half]
    #pragma unroll
    for (int kg = 0; kg < 4; ++kg)
        #pragma unroll
        for (int bi = 0; bi < 4; ++bi) {
            int b = bi * 16 + l15;
            int gi = (row0 + b) * 32 + kg * 8 + lhi * 2;
            xr[kg][bi * 2]     = xg[gi];
            xr[kg][bi * 2 + 1] = xg[gi + 1];
        }

    // ---- issue wsA loads (coalesced frag streams, L2-hot) ----
    bf16x8 wsA[4][4];                    // A[n][k], n = wv*64+hi*16+l15
    #pragma unroll
    for (int hi = 0; hi < 4; ++hi)
        #pragma unroll
        for (int kg = 0; kg < 4; ++kg)
            wsA[hi][kg] = __builtin_bit_cast(bf16x8,
                wsP[((kg * 4 + hi) * 4 + wv) * 64 + lane]);

    // ---- convert x -> B-frags in registers (releases xr) ----
    bf16x8 xb[4][4];                     // [kg][bi]
    #pragma unroll
    for (int kg = 0; kg < 4; ++kg)
        #pragma unroll
        for (int bi = 0; bi < 4; ++bi) {
            float4 a = xr[kg][bi * 2], d = xr[kg][bi * 2 + 1];
            uint4 u;
            u.x = pack2(a.x, a.y); u.y = pack2(a.z, a.w);
            u.z = pack2(d.x, d.y); u.w = pack2(d.z, d.w);
            xb[kg][bi] = __builtin_bit_cast(bf16x8, u);
        }

    // ---- issue wfB loads (latency hidden under GEMM1) ----
    bf16x8 wfB[8];                       // B[k][c], c = wv*16+l15
    #pragma unroll
    for (int kg = 0; kg < 8; ++kg)
        wfB[kg] = __builtin_bit_cast(bf16x8, wfP[(kg * 4 + wv) * 64 + lane]);

    // ---- GEMM1: h^T[n][b] = WsT @ x^T (pure register MFMA) ----
    f32x4 acc1[4][4];                    // [hi][bi]
    #pragma unroll
    for (int hi = 0; hi < 4; ++hi)
        #pragma unroll
        for (int bi = 0; bi < 4; ++bi)
            acc1[hi][bi] = (f32x4){0.f, 0.f, 0.f, 0.f};
    #pragma unroll
    for (int kg = 0; kg < 4; ++kg) {
        __builtin_amdgcn_s_setprio(1);
        #pragma unroll
        for (int hi = 0; hi < 4; ++hi)
            #pragma unroll
            for (int bi = 0; bi < 4; ++bi)
                acc1[hi][bi] = __builtin_amdgcn_mfma_f32_16x16x32_bf16(
                    wsA[hi][kg], xb[kg][bi], acc1[hi][bi], 0, 0, 0);
        __builtin_amdgcn_s_setprio(0);
    }

    // ---- small operands + routing table (land under h-write/BAR) ----
    f32x4 bsv[4];
    #pragma unroll
    for (int hi = 0; hi < 4; ++hi)
        bsv[hi] = *(const f32x4*)(bs + wv * 64 + hi * 16 + lhi * 4);
    const float bfv = bfuse[wv * 16 + l15];
    const int myE = wv * 2 + (l15 >> 3);
    const int co  = l15 & 7;
    int ev[16];
    #pragma unroll
    for (int mi = 0; mi < 4; ++mi)
        #pragma unroll
        for (int r = 0; r < 4; ++r)
            ev[mi * 4 + r] = phases[row0 + mi * 16 + lhi * 4 + r];

    // ---- h-write: relu(acc1 + bs), conflict-free ds_write_b64 ----
    #pragma unroll
    for (int hi = 0; hi < 4; ++hi)
        #pragma unroll
        for (int bi = 0; bi < 4; ++bi) {
            float v0 = acc1[hi][bi][0] + bsv[hi][0]; v0 = v0 > 0.f ? v0 : 0.f;
            float v1 = acc1[hi][bi][1] + bsv[hi][1]; v1 = v1 > 0.f ? v1 : 0.f;
            float v2 = acc1[hi][bi][2] + bsv[hi][2]; v2 = v2 > 0.f ? v2 : 0.f;
            float v3 = acc1[hi][bi][3] + bsv[hi][3]; v3 = v3 > 0.f ? v3 : 0.f;
            uint2 u; u.x = pack2(v0, v1); u.y = pack2(v2, v3);
            int b = bi * 16 + l15;
            int n0 = wv * 64 + hi * 16 + lhi * 4;
            unsigned addr = (unsigned)(b * 512 + n0 * 2);
            addr ^= (unsigned)((b & 7) << 4);
            *(uint2*)(hs + addr) = u;
        }
    __syncthreads();                     // hs ready (the ONLY barrier)

    // ---- GEMM2: y[b][c] = h @ WfT + bfuse ----
    f32x4 acc2[4];
    #pragma unroll
    for (int mi = 0; mi < 4; ++mi)
        acc2[mi] = (f32x4){bfv, bfv, bfv, bfv};
    #pragma unroll
    for (int kg = 0; kg < 8; ++kg) {
        bf16x8 ha[4];
        #pragma unroll
        for (int mi = 0; mi < 4; ++mi) {
            int b = mi * 16 + l15;
            unsigned addr = (unsigned)(b * 512 + (kg * 32 + lhi * 8) * 2);
            addr ^= (unsigned)((b & 7) << 4);
            ha[mi] = *(const bf16x8*)(hs + addr);
        }
        __builtin_amdgcn_s_setprio(1);
        #pragma unroll
        for (int mi = 0; mi < 4; ++mi)
            acc2[mi] = __builtin_amdgcn_mfma_f32_16x16x32_bf16(
                ha[mi], wfB[kg], acc2[mi], 0, 0, 0);
        __builtin_amdgcn_s_setprio(0);
    }

    // ---- routed predicated stores (ev preloaded) ----
    #pragma unroll
    for (int mi = 0; mi < 4; ++mi)
        #pragma unroll
        for (int r = 0; r < 4; ++r) {
            int b = mi * 16 + lhi * 4 + r;
            if (ev[mi * 4 + r] == myE)
                out[(size_t)(row0 + b) * 8 + co] = acc2[mi][r];
        }
}

extern "C" void kernel_launch(void* const* d_in, const int* in_sizes, int n_in,
                              void* d_out, int out_size, void* d_ws, size_t ws_size,
                              hipStream_t stream) {
    const float* x      = (const float*)d_in[0];
    const int*   phases = (const int*)d_in[1];
    const float* Ws     = (const float*)d_in[2];
    const float* bs     = (const float*)d_in[3];
    const float* W1     = (const float*)d_in[4];
    const float* b1     = (const float*)d_in[5];
    const float* W2     = (const float*)d_in[6];
    const float* b2     = (const float*)d_in[7];
    float* out = (float*)d_out;

    uint4*          wsP   = (uint4*)d_ws;
    unsigned short* wfP   = (unsigned short*)((char*)d_ws + 65536);
    float*          bfuse = (float*)((char*)d_ws + 98304);

    prep_kernel<<<273, 256, 0, stream>>>(Ws, b1, W1, W2, b2,
                                         wsP, wfP, bfuse);
    fused_kernel<<<1024, 256, 0, stream>>>(
        x, phases, bs, wsP, (const uint4*)wfP, bfuse, out);
}

// Round 12
// 23.333 us; speedup vs baseline: 4.2250x; 1.6353x over previous
//
#include <hip/hip_runtime.h>
#include <hip/hip_bf16.h>
#include <cstdint>

// B=65536, D=128, H=256, O=8, E=8
// Algebra: no activation between head Linears -> y = h @ (W1 W2) + (b1 W2 + b2).
// ws layout (weights pre-packed in MFMA FRAGMENT ORDER for coalesced loads):
//   wsP  uint4[4096]  @0      (64KB): wsP[((kg*4+hi)*4+wv)*64+lane] = A-frag of Ws^T
//   wfP  uint4[2048]  @65536  (32KB): wfP[(kg*4+wv)*64+lane]        = B-frag of (W1@W2)^T
//   bfuse f32[64]     @98304:          bfuse[e*8+o] = (b1[e]@W2[e])[o] + b2[e][o]

using bf16x8 = __attribute__((ext_vector_type(8))) __bf16;
using f32x4  = __attribute__((ext_vector_type(4))) float;

__device__ __forceinline__ unsigned short bf16b(float f) {
    __bf16 h = (__bf16)f;                       // RNE; pairs fuse to v_cvt_pk_bf16_f32
    return __builtin_bit_cast(unsigned short, h);
}
__device__ __forceinline__ unsigned pack2(float a, float b) {
    return (unsigned)bf16b(a) | ((unsigned)bf16b(b) << 16);
}

// ---------------------------------------------------------------------------
// Prep v5 (validated r9-r11): 273 blocks.
// ---------------------------------------------------------------------------
__global__ void prep_kernel(const float* __restrict__ Ws,
                            const float* __restrict__ b1,
                            const float* __restrict__ W1,
                            const float* __restrict__ W2,
                            const float* __restrict__ b2,
                            uint4* __restrict__ wsP,
                            unsigned short* __restrict__ wfP,
                            float* __restrict__ bfuse) {
    const int bid = blockIdx.x, tid = threadIdx.x;
    if (bid < 256) {
        __shared__ float w2sT[8][256];               // W2[e]^T : [o][k]
        const int e = bid >> 5, mc = bid & 31;
        const float* W2e = W2 + (size_t)e * 2048;
        float4 v0 = ((const float4*)W2e)[tid];
        float4 v1 = ((const float4*)W2e)[256 + tid];
        const int mloc = tid >> 5, kg = tid & 31;    // k = kg + i*32
        const int m = mc * 8 + mloc;
        const float* w1row = W1 + ((size_t)e * 256 + m) * 256;
        float w1v[8];
        #pragma unroll
        for (int i = 0; i < 8; ++i) w1v[i] = w1row[kg + i * 32];
        {
            int f4 = tid, k = f4 >> 1, o4 = (f4 & 1) * 4;
            w2sT[o4 + 0][k] = v0.x; w2sT[o4 + 1][k] = v0.y;
            w2sT[o4 + 2][k] = v0.z; w2sT[o4 + 3][k] = v0.w;
            f4 = 256 + tid; k = f4 >> 1; o4 = (f4 & 1) * 4;
            w2sT[o4 + 0][k] = v1.x; w2sT[o4 + 1][k] = v1.y;
            w2sT[o4 + 2][k] = v1.z; w2sT[o4 + 3][k] = v1.w;
        }
        __syncthreads();
        float acc[8] = {0,0,0,0,0,0,0,0};
        #pragma unroll
        for (int i = 0; i < 8; ++i) {
            int k = kg + i * 32;
            #pragma unroll
            for (int o = 0; o < 8; ++o) acc[o] += w1v[i] * w2sT[o][k];
        }
        #pragma unroll
        for (int o = 0; o < 8; ++o) {
            acc[o] += __shfl_xor(acc[o], 1);
            acc[o] += __shfl_xor(acc[o], 2);
            acc[o] += __shfl_xor(acc[o], 4);
            acc[o] += __shfl_xor(acc[o], 8);
            acc[o] += __shfl_xor(acc[o], 16);
        }
        if (kg == 0) {
            const int kgf  = m >> 5;
            const int lhif = (m >> 3) & 3;
            const int j    = m & 7;
            #pragma unroll
            for (int o = 0; o < 8; ++o) {
                int c = e * 8 + o;
                int lanef = lhif * 16 + (c & 15);
                int F = (kgf * 4 + (c >> 4)) * 64 + lanef;
                wfP[(size_t)F * 8 + j] = bf16b(acc[o]);
            }
        }
    } else if (bid < 272) {
        const int b2i = bid - 256;
        const int kg = b2i >> 2, hi = b2i & 3;
        const int wv = tid >> 6, lane = tid & 63;
        const int l15 = lane & 15, lhi = lane >> 4;
        const int n  = wv * 64 + hi * 16 + l15;
        const int k0 = kg * 32 + lhi * 8;
        float w[8];
        #pragma unroll
        for (int j = 0; j < 8; ++j)
            w[j] = Ws[(size_t)(k0 + j) * 256 + n];
        uint4 u;
        u.x = pack2(w[0], w[1]); u.y = pack2(w[2], w[3]);
        u.z = pack2(w[4], w[5]); u.w = pack2(w[6], w[7]);
        wsP[((kg * 4 + hi) * 4 + wv) * 64 + lane] = u;
    } else {
        const int e = tid >> 5, l = tid & 31;
        float acc[8] = {0,0,0,0,0,0,0,0};
        #pragma unroll
        for (int i = 0; i < 8; ++i) {
            int k = l * 8 + i;
            float a = b1[e * 256 + k];
            const float* w2r = W2 + ((size_t)(e * 256 + k)) * 8;
            #pragma unroll
            for (int o = 0; o < 8; ++o) acc[o] += a * w2r[o];
        }
        #pragma unroll
        for (int o = 0; o < 8; ++o) {
            acc[o] += __shfl_xor(acc[o], 1);
            acc[o] += __shfl_xor(acc[o], 2);
            acc[o] += __shfl_xor(acc[o], 4);
            acc[o] += __shfl_xor(acc[o], 8);
            acc[o] += __shfl_xor(acc[o], 16);
        }
        if (l == 0) {
            #pragma unroll
            for (int o = 0; o < 8; ++o)
                bfuse[e * 8 + o] = acc[o] + b2[e * 8 + o];
        }
    }
}

// ---------------------------------------------------------------------------
// Fused v10: max-TLP shallow blocks. 32 rows/block, grid=2048 (4 rolling
// generations over ~512 resident slots -> load phases of new blocks overlap
// compute of finishing ones). LDS 24KB (xs 8K + hs 16K); cooperative x
// staging (r11 lesson: never per-wave-redundant x). wfB loaded after GEMM1
// (keeps peak VGPR ~150). No min-waves bound (r6/r7 spill lesson). Body
// math byte-identical to r5-validated kernel.
// ---------------------------------------------------------------------------
__global__ __launch_bounds__(256) void fused_kernel(
    const float* __restrict__ x,
    const int* __restrict__ phases,
    const float* __restrict__ bs,
    const uint4* __restrict__ wsP,
    const uint4* __restrict__ wfP,
    const float* __restrict__ bfuse,
    float* __restrict__ out) {
    __shared__ __align__(16) char lds[8192 + 16384];
    char* xs = lds;                      // [32][128] bf16, swz: addr ^= (row&7)<<4
    char* hs = lds + 8192;               // [32][256] bf16, swz: addr ^= (row&7)<<4

    const int tid = threadIdx.x;
    const int lane = tid & 63;
    const int wv = tid >> 6;
    const int l15 = lane & 15;
    const int lhi = lane >> 4;
    const int row0 = blockIdx.x * 32;

    const float4* xg = (const float4*)x;

    // ---- issue x loads (one 16KB tile, cooperative: 2 chunk-pairs/thread) ----
    float4 a0[2], d0[2];
    #pragma unroll
    for (int it = 0; it < 2; ++it) {
        int c = it * 256 + tid;          // chunk of 8 floats; 512 chunks total
        int row = c >> 4, col8 = c & 15;
        int gi = (row0 + row) * 32 + col8 * 2;
        a0[it] = xg[gi]; d0[it] = xg[gi + 1];
    }

    // ---- issue wsA loads (coalesced frag streams, L2-hot) ----
    bf16x8 wsA[4][4];                    // A[n][k], n = wv*64+hi*16+l15
    #pragma unroll
    for (int hi = 0; hi < 4; ++hi)
        #pragma unroll
        for (int kg = 0; kg < 4; ++kg)
            wsA[hi][kg] = __builtin_bit_cast(bf16x8,
                wsP[((kg * 4 + hi) * 4 + wv) * 64 + lane]);

    // ---- small operands (hide under x/weight latency) ----
    f32x4 bsv[4];
    #pragma unroll
    for (int hi = 0; hi < 4; ++hi)
        bsv[hi] = *(const f32x4*)(bs + wv * 64 + hi * 16 + lhi * 4);
    const float bfv = bfuse[wv * 16 + l15];
    const int myE = wv * 2 + (l15 >> 3);
    const int co  = l15 & 7;
    int ev[8];
    #pragma unroll
    for (int mi = 0; mi < 2; ++mi)
        #pragma unroll
        for (int r = 0; r < 4; ++r)
            ev[mi * 4 + r] = phases[row0 + mi * 16 + lhi * 4 + r];

    // ---- convert + write xs ----
    #pragma unroll
    for (int it = 0; it < 2; ++it) {
        int c = it * 256 + tid;
        int row = c >> 4, col8 = c & 15;
        unsigned addr = (unsigned)(row * 256 + col8 * 16);
        addr ^= (unsigned)((row & 7) << 4);
        uint4 u;
        u.x = pack2(a0[it].x, a0[it].y); u.y = pack2(a0[it].z, a0[it].w);
        u.z = pack2(d0[it].x, d0[it].y); u.w = pack2(d0[it].z, d0[it].w);
        *(uint4*)(xs + addr) = u;
    }
    __syncthreads();                     // xs ready

    // ---- GEMM1: h^T[n][b] = WsT @ x^T ----
    f32x4 acc1[4][2];                    // [hi][bi]
    #pragma unroll
    for (int hi = 0; hi < 4; ++hi)
        #pragma unroll
        for (int bi = 0; bi < 2; ++bi)
            acc1[hi][bi] = (f32x4){0.f, 0.f, 0.f, 0.f};
    #pragma unroll
    for (int kg = 0; kg < 4; ++kg) {
        bf16x8 xb[2];
        #pragma unroll
        for (int bi = 0; bi < 2; ++bi) {
            int b = bi * 16 + l15;
            unsigned addr = (unsigned)(b * 256 + (kg * 32 + lhi * 8) * 2);
            addr ^= (unsigned)((b & 7) << 4);
            xb[bi] = *(const bf16x8*)(xs + addr);
        }
        __builtin_amdgcn_s_setprio(1);
        #pragma unroll
        for (int hi = 0; hi < 4; ++hi)
            #pragma unroll
            for (int bi = 0; bi < 2; ++bi)
                acc1[hi][bi] = __builtin_amdgcn_mfma_f32_16x16x32_bf16(
                    wsA[hi][kg], xb[bi], acc1[hi][bi], 0, 0, 0);
        __builtin_amdgcn_s_setprio(0);
    }

    // ---- issue wfB loads (latency hidden under h-write + barrier) ----
    bf16x8 wfB[8];                       // B[k][c], c = wv*16+l15
    #pragma unroll
    for (int kg = 0; kg < 8; ++kg)
        wfB[kg] = __builtin_bit_cast(bf16x8, wfP[(kg * 4 + wv) * 64 + lane]);

    // ---- h-write: relu(acc1 + bs), conflict-free ds_write_b64 ----
    #pragma unroll
    for (int hi = 0; hi < 4; ++hi)
        #pragma unroll
        for (int bi = 0; bi < 2; ++bi) {
            float v0 = acc1[hi][bi][0] + bsv[hi][0]; v0 = v0 > 0.f ? v0 : 0.f;
            float v1 = acc1[hi][bi][1] + bsv[hi][1]; v1 = v1 > 0.f ? v1 : 0.f;
            float v2 = acc1[hi][bi][2] + bsv[hi][2]; v2 = v2 > 0.f ? v2 : 0.f;
            float v3 = acc1[hi][bi][3] + bsv[hi][3]; v3 = v3 > 0.f ? v3 : 0.f;
            uint2 u; u.x = pack2(v0, v1); u.y = pack2(v2, v3);
            int b = bi * 16 + l15;
            int n0 = wv * 64 + hi * 16 + lhi * 4;
            unsigned addr = (unsigned)(b * 512 + n0 * 2);
            addr ^= (unsigned)((b & 7) << 4);
            *(uint2*)(hs + addr) = u;
        }
    __syncthreads();                     // hs ready

    // ---- GEMM2: y[b][c] = h @ WfT + bfuse ----
    f32x4 acc2[2];
    #pragma unroll
    for (int mi = 0; mi < 2; ++mi)
        acc2[mi] = (f32x4){bfv, bfv, bfv, bfv};
    #pragma unroll
    for (int kg = 0; kg < 8; ++kg) {
        bf16x8 ha[2];
        #pragma unroll
        for (int mi = 0; mi < 2; ++mi) {
            int b = mi * 16 + l15;
            unsigned addr = (unsigned)(b * 512 + (kg * 32 + lhi * 8) * 2);
            addr ^= (unsigned)((b & 7) << 4);
            ha[mi] = *(const bf16x8*)(hs + addr);
        }
        __builtin_amdgcn_s_setprio(1);
        #pragma unroll
        for (int mi = 0; mi < 2; ++mi)
            acc2[mi] = __builtin_amdgcn_mfma_f32_16x16x32_bf16(
                ha[mi], wfB[kg], acc2[mi], 0, 0, 0);
        __builtin_amdgcn_s_setprio(0);
    }

    // ---- routed predicated stores (ev preloaded) ----
    #pragma unroll
    for (int mi = 0; mi < 2; ++mi)
        #pragma unroll
        for (int r = 0; r < 4; ++r) {
            int b = mi * 16 + lhi * 4 + r;
            if (ev[mi * 4 + r] == myE)
                out[(size_t)(row0 + b) * 8 + co] = acc2[mi][r];
        }
}

extern "C" void kernel_launch(void* const* d_in, const int* in_sizes, int n_in,
                              void* d_out, int out_size, void* d_ws, size_t ws_size,
                              hipStream_t stream) {
    const float* x      = (const float*)d_in[0];
    const int*   phases = (const int*)d_in[1];
    const float* Ws     = (const float*)d_in[2];
    const float* bs     = (const float*)d_in[3];
    const float* W1     = (const float*)d_in[4];
    const float* b1     = (const float*)d_in[5];
    const float* W2     = (const float*)d_in[6];
    const float* b2     = (const float*)d_in[7];
    float* out = (float*)d_out;

    uint4*          wsP   = (uint4*)d_ws;
    unsigned short* wfP   = (unsigned short*)((char*)d_ws + 65536);
    float*          bfuse = (float*)((char*)d_ws + 98304);

    prep_kernel<<<273, 256, 0, stream>>>(Ws, b1, W1, W2, b2,
                                         wsP, wfP, bfuse);
    fused_kernel<<<2048, 256, 0, stream>>>(
        x, phases, bs, wsP, (const uint4*)wfP, bfuse, out);
}